// Round 6
// baseline (387.401 us; speedup 1.0000x reference)
//
#include <hip/hip_runtime.h>
#include <hip/hip_fp16.h>
#include <math.h>

#define N_NODES 50000
#define N_EDGES 800000
#define NGRAPH  512
#define BN_EPS  1e-5f
#define SCAN_BLOCKS 196   // ceil(50000/256)

// ---------------- degree count (int) ----------------
__global__ void k_deg(const int* __restrict__ dst, int* __restrict__ cnt) {
    int e = blockIdx.x * blockDim.x + threadIdx.x;
    if (e < N_EDGES) atomicAdd(&cnt[dst[e]], 1);
}

// ------- scan A: per-256-chunk exclusive scan (coalesced) + dinv fused ------
__global__ __launch_bounds__(256) void k_scanA(const int* __restrict__ cnt,
        float* __restrict__ dinv, int* __restrict__ local, int* __restrict__ bsum) {
    int t = threadIdx.x;
    int n = blockIdx.x * 256 + t;
    int v = 0;
    if (n < N_NODES) {
        v = cnt[n];
        dinv[n] = rsqrtf((float)v + 1.0f);
    }
    __shared__ int sh[256];
    sh[t] = v;
    __syncthreads();
    for (int off = 1; off < 256; off <<= 1) {
        int u = (t >= off) ? sh[t - off] : 0;
        __syncthreads();
        sh[t] += u;
        __syncthreads();
    }
    if (n < N_NODES) local[n] = sh[t] - v;
    if (t == 255) bsum[blockIdx.x] = sh[255];
}

// ------- scan B: exclusive scan of 196 block sums (1 tiny block) ------
__global__ __launch_bounds__(256) void k_scanB(int* __restrict__ bsum) {
    int t = threadIdx.x;
    int v = (t < SCAN_BLOCKS) ? bsum[t] : 0;
    __shared__ int sh[256];
    sh[t] = v;
    __syncthreads();
    for (int off = 1; off < 256; off <<= 1) {
        int u = (t >= off) ? sh[t - off] : 0;
        __syncthreads();
        sh[t] += u;
        __syncthreads();
    }
    if (t < SCAN_BLOCKS) bsum[t] = sh[t] - v;   // exclusive block offsets
}

// ------- scan C: row_start = local + block offset ------
__global__ void k_scanC(const int* __restrict__ local, const int* __restrict__ bsum,
                        int* __restrict__ row_start) {
    int n = blockIdx.x * blockDim.x + threadIdx.x;
    if (n < N_NODES) row_start[n] = local[n] + bsum[n >> 8];
}

// ------- CSR fill: entry = (fp16 coef << 16) | src (src < 65536) -------
__global__ void k_fill(const int* __restrict__ src, const int* __restrict__ dst,
                       const int* __restrict__ row_start, int* __restrict__ cursor,
                       const float* __restrict__ dinv, unsigned* __restrict__ entries) {
    int e = blockIdx.x * blockDim.x + threadIdx.x;
    if (e >= N_EDGES) return;
    int s = src[e], t = dst[e];
    int pos = row_start[t] + atomicAdd(&cursor[t], 1);
    float co = dinv[s] * dinv[t];
    unsigned cb = (unsigned)__half_as_ushort(__float2half(co));
    entries[pos] = (cb << 16) | (unsigned)s;
}

// ---------------- layer-1 gather (4 channels) + self term ----------------
__global__ void k_gather1(const int* __restrict__ row_start, const int* __restrict__ cnt,
                          const unsigned* __restrict__ entries, const float* __restrict__ dinv,
                          const float4* __restrict__ x, float4* __restrict__ aggx) {
    int n = blockIdx.x * blockDim.x + threadIdx.x;
    if (n >= N_NODES) return;
    float di = dinv[n], c = di * di;
    float4 a = x[n];
    float4 acc = make_float4(a.x * c, a.y * c, a.z * c, a.w * c);
    int rs = row_start[n], cn = cnt[n];
    const unsigned* ep = entries + rs;
    for (int i = 0; i < cn; i++) {
        unsigned e = ep[i];
        int s = (int)(e & 0xFFFFu);
        float co = __half2float(__ushort_as_half((unsigned short)(e >> 16)));
        float4 v = x[s];
        acc.x = fmaf(v.x, co, acc.x);
        acc.y = fmaf(v.y, co, acc.y);
        acc.z = fmaf(v.z, co, acc.z);
        acc.w = fmaf(v.w, co, acc.w);
    }
    aggx[n] = acc;
}

// ---------------- BN1 stats (h1 recomputed on the fly, never stored) --------
__global__ __launch_bounds__(128) void k_stats1(const float4* __restrict__ aggx,
        const float* __restrict__ W1, const float* __restrict__ b1,
        float* __restrict__ s1, float* __restrict__ q1) {
    __shared__ float w1s[4][128];
    int j = threadIdx.x;
    for (int c = 0; c < 4; c++) w1s[c][j] = W1[c * 128 + j];
    float bj = b1[j];
    __syncthreads();
    int per = (N_NODES + gridDim.x - 1) / gridDim.x;
    int n0 = blockIdx.x * per, n1 = min(n0 + per, N_NODES);
    float ps = 0.f, pq = 0.f;
    for (int n = n0; n < n1; n++) {
        float4 a = aggx[n];
        float h = fmaf(a.x, w1s[0][j], fmaf(a.y, w1s[1][j],
                  fmaf(a.z, w1s[2][j], fmaf(a.w, w1s[3][j], bj))));
        h = fmaxf(h, 0.f);
        ps += h; pq += h * h;
    }
    atomicAdd(&s1[j], ps);
    atomicAdd(&q1[j], pq);
}

// ------- fused: BN1-fold + recompute h1 tile + GEMM vs folded W2 -> h2 ------
// h2 layout: [2][N][32] halfs (channel-split for the two gather2 passes)
__global__ __launch_bounds__(256) void k_h2(const float4* __restrict__ aggx,
        const float* __restrict__ W1, const float* __restrict__ b1,
        const float* __restrict__ s1, const float* __restrict__ q1,
        const float* __restrict__ g1, const float* __restrict__ be1,
        const float* __restrict__ W2, __half* __restrict__ h2h) {
    __shared__ float w[128 * 64];
    __shared__ float hs[16][128];
    __shared__ float w1s[4][128];
    __shared__ float b1s[128];
    __shared__ float afold[128], cfold[128];
    int tid = threadIdx.x;
    for (int i = tid; i < 8192; i += 256) w[i] = W2[i];   // raw W2
    if (tid < 128) {
        b1s[tid] = b1[tid];
        for (int c = 0; c < 4; c++) w1s[c][tid] = W1[c * 128 + tid];
        float mean = s1[tid] / (float)N_NODES;
        float var  = q1[tid] / (float)N_NODES - mean * mean;
        float aa   = rsqrtf(var + BN_EPS) * g1[tid];
        afold[tid] = aa;
        cfold[tid] = be1[tid] - mean * aa;
    }
    __syncthreads();
    int j = tid & 63, q = tid >> 6;
    // d2[j] = sum_k cfold[k] * W2[k*64+j]  (raw W2 in LDS)
    float dj = 0.f;
    for (int k = 0; k < 128; k++) dj = fmaf(cfold[k], w[k * 64 + j], dj);
    // h1 tiles
    int n0 = blockIdx.x * 16;   // grid exactly N_NODES/16
    for (int i = tid; i < 2048; i += 256) {
        int nn = n0 + (i >> 7), jj = i & 127;
        float4 a = aggx[nn];
        float h = fmaf(a.x, w1s[0][jj], fmaf(a.y, w1s[1][jj],
                  fmaf(a.z, w1s[2][jj], fmaf(a.w, w1s[3][jj], b1s[jj]))));
        hs[i >> 7][jj] = fmaxf(h, 0.f);
    }
    __syncthreads();
    // scale W2 in place by afold[k]
    for (int i = tid; i < 8192; i += 256) w[i] *= afold[i >> 6];
    __syncthreads();
    float acc0 = 0.f, acc1 = 0.f, acc2 = 0.f, acc3 = 0.f;
    for (int k = 0; k < 128; k++) {
        float wv = w[k * 64 + j];
        acc0 = fmaf(hs[q * 4 + 0][k], wv, acc0);
        acc1 = fmaf(hs[q * 4 + 1][k], wv, acc1);
        acc2 = fmaf(hs[q * 4 + 2][k], wv, acc2);
        acc3 = fmaf(hs[q * 4 + 3][k], wv, acc3);
    }
    float av[4] = {acc0, acc1, acc2, acc3};
    int half_idx = j >> 5, c32 = j & 31;
#pragma unroll
    for (int i = 0; i < 4; i++) {
        int n = n0 + q * 4 + i;
        h2h[half_idx * (N_NODES * 32) + n * 32 + c32] = __float2half(av[i] + dj);
    }
}

// ------- layer-2 gather, one 32-channel pass: 4 nodes/wave (16 lanes each),
//         entry coop-load + width-16 shfl broadcast, fused relu+b2+stats -----
__global__ __launch_bounds__(256) void k_gather2(const int* __restrict__ row_start,
        const int* __restrict__ cnt, const unsigned* __restrict__ entries,
        const float* __restrict__ dinv, const __half2* __restrict__ h2p,
        const float* __restrict__ b2p, __half2* __restrict__ outp,
        float* __restrict__ s2p, float* __restrict__ q2p) {
    int lane = threadIdx.x & 63;
    int sub = lane >> 4;            // node subgroup 0..3
    int j = lane & 15;              // half2 index: channels 2j, 2j+1 of this pass
    int wid = blockIdx.x * 4 + (threadIdx.x >> 6);
    int n = wid * 4 + sub;
    bool valid = (n < N_NODES);
    int nn = valid ? n : 0;
    float2 ps = make_float2(0.f, 0.f), pq = make_float2(0.f, 0.f);
    float2 bj = make_float2(b2p[2 * j], b2p[2 * j + 1]);

    int rs = row_start[nn];
    int cn = valid ? cnt[nn] : 0;
    float di = dinv[nn];
    float sc = di * di;
    float2 self = __half22float2(h2p[nn * 16 + j]);
    float2 acc0 = make_float2(self.x * sc, self.y * sc);
    float2 acc1 = make_float2(0.f, 0.f);
    // max count across the wave's 4 subgroups
    int cm = cn;
    cm = max(cm, __shfl_xor(cm, 16));
    cm = max(cm, __shfl_xor(cm, 32));
    const unsigned* ep = entries + rs;
    int i = 0;
    while (i < cm) {
        int um = min(16, cm - i);
        int myRem = min(16, max(0, cn - i));
        unsigned e = (j < myRem) ? ep[i + j] : 0u;   // coef bits 0 -> fma no-op
        int k = 0;
        for (; k + 1 < um; k += 2) {
            int e0 = __shfl((int)e, k, 16);
            int e1 = __shfl((int)e, k + 1, 16);
            float c0 = __half2float(__ushort_as_half((unsigned short)((unsigned)e0 >> 16)));
            float c1 = __half2float(__ushort_as_half((unsigned short)((unsigned)e1 >> 16)));
            float2 v0 = __half22float2(h2p[(e0 & 0xFFFF) * 16 + j]);
            float2 v1 = __half22float2(h2p[(e1 & 0xFFFF) * 16 + j]);
            acc0.x = fmaf(v0.x, c0, acc0.x);
            acc0.y = fmaf(v0.y, c0, acc0.y);
            acc1.x = fmaf(v1.x, c1, acc1.x);
            acc1.y = fmaf(v1.y, c1, acc1.y);
        }
        if (k < um) {
            int e0 = __shfl((int)e, k, 16);
            float c0 = __half2float(__ushort_as_half((unsigned short)((unsigned)e0 >> 16)));
            float2 v0 = __half22float2(h2p[(e0 & 0xFFFF) * 16 + j]);
            acc0.x = fmaf(v0.x, c0, acc0.x);
            acc0.y = fmaf(v0.y, c0, acc0.y);
        }
        i += 16;
    }
    if (valid) {
        float vx = fmaxf(acc0.x + acc1.x + bj.x, 0.f);
        float vy = fmaxf(acc0.y + acc1.y + bj.y, 0.f);
        outp[n * 32 + j] = __floats2half2_rn(vx, vy);
        ps.x += vx; ps.y += vy;
        pq.x += vx * vx; pq.y += vy * vy;
    }
    __shared__ float ssum[32], sq[32];
    if (threadIdx.x < 32) { ssum[threadIdx.x] = 0.f; sq[threadIdx.x] = 0.f; }
    __syncthreads();
    atomicAdd(&ssum[2 * j], ps.x);
    atomicAdd(&ssum[2 * j + 1], ps.y);
    atomicAdd(&sq[2 * j], pq.x);
    atomicAdd(&sq[2 * j + 1], pq.y);
    __syncthreads();
    if (threadIdx.x < 32) {
        atomicAdd(&s2p[threadIdx.x], ssum[threadIdx.x]);
        atomicAdd(&q2p[threadIdx.x], sq[threadIdx.x]);
    }
}

// ---- global_add_pool (batch sorted: run-accumulate), BN2 affine fused ----
__global__ __launch_bounds__(64) void k_pool(const __half* __restrict__ out2,
        const int* __restrict__ batch, const float* __restrict__ s2,
        const float* __restrict__ q2, const float* __restrict__ g2,
        const float* __restrict__ be2, float* __restrict__ hg) {
    int j = threadIdx.x;
    float mean = s2[j] / (float)N_NODES;
    float var  = q2[j] / (float)N_NODES - mean * mean;
    float a = rsqrtf(var + BN_EPS) * g2[j];
    float c = be2[j] - mean * a;
    int per = (N_NODES + gridDim.x - 1) / gridDim.x;
    int n0 = blockIdx.x * per, n1 = min(n0 + per, N_NODES);
    float acc = 0.f;
    int cur = -1;
    for (int n = n0; n < n1; n++) {
        int g = batch[n];
        float v = fmaf(__half2float(out2[n * 64 + j]), a, c);
        if (g != cur) {
            if (cur >= 0) atomicAdd(&hg[cur * 64 + j], acc);
            cur = g; acc = v;
        } else {
            acc += v;
        }
    }
    if (cur >= 0) atomicAdd(&hg[cur * 64 + j], acc);
}

// ---------------- fc1 + relu + BN3 stats ----------------
__global__ __launch_bounds__(256) void k_fc1(const float* __restrict__ hg,
        const float* __restrict__ fW1, const float* __restrict__ fb1,
        float* __restrict__ t1, float* __restrict__ s3, float* __restrict__ q3) {
    __shared__ float w[64 * 64];
    int tid = threadIdx.x;
    for (int i = tid; i < 4096; i += 256) w[i] = fW1[i];
    __syncthreads();
    int j = tid & 63, q = tid >> 6;
    float bj = fb1[j];
    float ps = 0.f, pq = 0.f;
    for (int r = blockIdx.x * 4 + q; r < NGRAPH; r += gridDim.x * 4) {
        float acc = bj;
        for (int k = 0; k < 64; k++) acc = fmaf(hg[r * 64 + k], w[k * 64 + j], acc);
        acc = fmaxf(acc, 0.f);
        t1[r * 64 + j] = acc;
        ps += acc; pq += acc * acc;
    }
    atomicAdd(&s3[j], ps);
    atomicAdd(&q3[j], pq);
}

// ------- bn3 (affine from stats, fused) -> fc2+relu -> fc3 -> log_softmax ---
__global__ __launch_bounds__(256) void k_final(const float* __restrict__ t1,
        const float* __restrict__ s3, const float* __restrict__ q3,
        const float* __restrict__ g3, const float* __restrict__ be3,
        const float* __restrict__ fW2, const float* __restrict__ fb2,
        const float* __restrict__ fW3, const float* __restrict__ fb3,
        float* __restrict__ out) {
    __shared__ float w2[64 * 64];
    __shared__ float w3s[192];
    __shared__ float a3[64], c3[64], b3s[3];
    int tid = threadIdx.x;
    for (int i = tid; i < 4096; i += 256) w2[i] = fW2[i];
    if (tid < 192) w3s[tid] = fW3[tid];
    if (tid < 64) {
        float mean = s3[tid] / (float)NGRAPH;
        float var  = q3[tid] / (float)NGRAPH - mean * mean;
        float a = rsqrtf(var + BN_EPS) * g3[tid];
        a3[tid] = a;
        c3[tid] = be3[tid] - mean * a;
    }
    if (tid < 3)  b3s[tid] = fb3[tid];
    __syncthreads();
    int lane = tid & 63, wv = tid >> 6;
    float fbj = fb2[lane];
    for (int r = blockIdx.x * 4 + wv; r < NGRAPH; r += gridDim.x * 4) {
        float acc = fbj;
        for (int k = 0; k < 64; k++) {
            float xk = fmaf(t1[r * 64 + k], a3[k], c3[k]);
            acc = fmaf(xk, w2[k * 64 + lane], acc);
        }
        acc = fmaxf(acc, 0.f);
        float o0 = acc * w3s[lane * 3 + 0];
        float o1 = acc * w3s[lane * 3 + 1];
        float o2 = acc * w3s[lane * 3 + 2];
        for (int off = 32; off; off >>= 1) {
            o0 += __shfl_down(o0, off);
            o1 += __shfl_down(o1, off);
            o2 += __shfl_down(o2, off);
        }
        if (lane == 0) {
            o0 += b3s[0]; o1 += b3s[1]; o2 += b3s[2];
            float m = fmaxf(o0, fmaxf(o1, o2));
            float lse = m + logf(expf(o0 - m) + expf(o1 - m) + expf(o2 - m));
            out[r * 3 + 0] = o0 - lse;
            out[r * 3 + 1] = o1 - lse;
            out[r * 3 + 2] = o2 - lse;
        }
    }
}

extern "C" void kernel_launch(void* const* d_in, const int* in_sizes, int n_in,
                              void* d_out, int out_size, void* d_ws, size_t ws_size,
                              hipStream_t stream) {
    const float* x   = (const float*)d_in[0];
    const int*   ei  = (const int*)d_in[1];
    const int*   bat = (const int*)d_in[2];
    const float* W1  = (const float*)d_in[3];
    const float* b1  = (const float*)d_in[4];
    const float* g1  = (const float*)d_in[5];
    const float* be1 = (const float*)d_in[6];
    const float* W2  = (const float*)d_in[7];
    const float* b2  = (const float*)d_in[8];
    const float* g2  = (const float*)d_in[9];
    const float* be2 = (const float*)d_in[10];
    const float* fW1 = (const float*)d_in[11];
    const float* fb1 = (const float*)d_in[12];
    const float* g3  = (const float*)d_in[13];
    const float* be3 = (const float*)d_in[14];
    const float* fW2 = (const float*)d_in[15];
    const float* fb2 = (const float*)d_in[16];
    const float* fW3 = (const float*)d_in[17];
    const float* fb3 = (const float*)d_in[18];

    // ---- workspace layout ----
    // zeroed region: cnt | cursor | hg | s1 q1 s2 q2 s3 q3
    int*   cnt    = (int*)d_ws;                       // N
    int*   cursor = cnt + N_NODES;                    // N
    float* hg     = (float*)(cursor + N_NODES);       // 512*64
    float* s1     = hg + NGRAPH * 64;                 // 128
    float* q1     = s1 + 128;                         // 128
    float* s2     = q1 + 128;                         // 64
    float* q2     = s2 + 64;                          // 64
    float* s3     = q2 + 64;                          // 64
    float* q3     = s3 + 64;                          // 64
    size_t zero_bytes = ((size_t)N_NODES * 2 + NGRAPH * 64 + 512) * 4;
    // non-zeroed scratch
    float* dinv   = q3 + 64;                          // N
    int*   row_start = (int*)(dinv + N_NODES);        // N
    int*   slocal = row_start + N_NODES;              // N   (scan locals)
    int*   sbsum  = slocal + N_NODES;                 // SCAN_BLOCKS (pad 256)
    unsigned* entries = (unsigned*)(sbsum + 256);     // E (4B each)
    float* aggx   = (float*)(entries + N_EDGES);      // N*4 (16B aligned)
    __half* h2    = (__half*)(aggx + (size_t)N_NODES * 4);   // [2][N][32] halfs
    __half* out2  = h2 + (size_t)N_NODES * 64;        // [N][64] halfs
    float* t1     = (float*)(out2 + (size_t)N_NODES * 64);   // 512*64

    hipMemsetAsync(d_ws, 0, zero_bytes, stream);

    const int* src = ei;
    const int* dst = ei + N_EDGES;

    k_deg    <<<(N_EDGES + 255) / 256, 256, 0, stream>>>(dst, cnt);
    k_scanA  <<<SCAN_BLOCKS, 256, 0, stream>>>(cnt, dinv, slocal, sbsum);
    k_scanB  <<<1, 256, 0, stream>>>(sbsum);
    k_scanC  <<<SCAN_BLOCKS, 256, 0, stream>>>(slocal, sbsum, row_start);
    k_fill   <<<(N_EDGES + 255) / 256, 256, 0, stream>>>(src, dst, row_start, cursor, dinv, entries);
    k_gather1<<<(N_NODES + 255) / 256, 256, 0, stream>>>(row_start, cnt, entries, dinv, (const float4*)x, (float4*)aggx);
    k_stats1 <<<512, 128, 0, stream>>>((const float4*)aggx, W1, b1, s1, q1);
    k_h2     <<<N_NODES / 16, 256, 0, stream>>>((const float4*)aggx, W1, b1, s1, q1, g1, be1, W2, h2);
    // two channel-split gather passes (pass p covers channels p*32..p*32+31)
    for (int p = 0; p < 2; p++) {
        const __half2* h2p = (const __half2*)h2 + (size_t)p * N_NODES * 16;
        __half2* outp = (__half2*)out2 + p * 16;
        k_gather2<<<3125, 256, 0, stream>>>(row_start, cnt, entries, dinv,
                                            h2p, b2 + p * 32, outp,
                                            s2 + p * 32, q2 + p * 32);
    }
    k_pool   <<<1024, 64, 0, stream>>>(out2, bat, s2, q2, g2, be2, hg);
    k_fc1    <<<16, 256, 0, stream>>>(hg, fW1, fb1, t1, s3, q3);
    k_final  <<<16, 256, 0, stream>>>(t1, s3, q3, g3, be3, fW2, fb2, fW3, fb3, (float*)d_out);
}

// Round 7
// 278.755 us; speedup vs baseline: 1.3898x; 1.3898x over previous
//
#include <hip/hip_runtime.h>
#include <hip/hip_fp16.h>
#include <math.h>

#define N_NODES 50000
#define N_EDGES 800000
#define NGRAPH  512
#define BN_EPS  1e-5f
#define SCAN_BLOCKS 196   // ceil(50000/256)

// ---------------- degree count (int) ----------------
__global__ void k_deg(const int* __restrict__ dst, int* __restrict__ cnt) {
    int e = blockIdx.x * blockDim.x + threadIdx.x;
    if (e < N_EDGES) atomicAdd(&cnt[dst[e]], 1);
}

// ------- scan A: per-256-chunk exclusive scan (coalesced) + dinv fused ------
__global__ __launch_bounds__(256) void k_scanA(const int* __restrict__ cnt,
        float* __restrict__ dinv, int* __restrict__ local, int* __restrict__ bsum) {
    int t = threadIdx.x;
    int n = blockIdx.x * 256 + t;
    int v = 0;
    if (n < N_NODES) {
        v = cnt[n];
        dinv[n] = rsqrtf((float)v + 1.0f);
    }
    __shared__ int sh[256];
    sh[t] = v;
    __syncthreads();
    for (int off = 1; off < 256; off <<= 1) {
        int u = (t >= off) ? sh[t - off] : 0;
        __syncthreads();
        sh[t] += u;
        __syncthreads();
    }
    if (n < N_NODES) local[n] = sh[t] - v;
    if (t == 255) bsum[blockIdx.x] = sh[255];
}

// ------- scan BC fused: every block scans the 196 block sums in LDS,
//         then writes row_start for its own 256-node chunk ------
__global__ __launch_bounds__(256) void k_scanBC(const int* __restrict__ bsum,
        const int* __restrict__ local, int* __restrict__ row_start) {
    __shared__ int sh[256];
    __shared__ int boff;
    int t = threadIdx.x;
    int v = (t < SCAN_BLOCKS) ? bsum[t] : 0;
    sh[t] = v;
    __syncthreads();
    for (int off = 1; off < 256; off <<= 1) {
        int u = (t >= off) ? sh[t - off] : 0;
        __syncthreads();
        sh[t] += u;
        __syncthreads();
    }
    if (t == blockIdx.x) boff = sh[t] - v;   // exclusive offset for this block
    __syncthreads();
    int n = blockIdx.x * 256 + t;
    if (n < N_NODES) row_start[n] = local[n] + boff;
}

// ------- CSR fill: entry = (fp16 coef << 16) | src (src < 65536) -------
__global__ void k_fill(const int* __restrict__ src, const int* __restrict__ dst,
                       const int* __restrict__ row_start, int* __restrict__ cursor,
                       const float* __restrict__ dinv, unsigned* __restrict__ entries) {
    int e = blockIdx.x * blockDim.x + threadIdx.x;
    if (e >= N_EDGES) return;
    int s = src[e], t = dst[e];
    int pos = row_start[t] + atomicAdd(&cursor[t], 1);
    float co = dinv[s] * dinv[t];
    unsigned cb = (unsigned)__half_as_ushort(__float2half(co));
    entries[pos] = (cb << 16) | (unsigned)s;
}

// ------- layer-1 gather: 2 threads/node, 4-deep load pipeline ----------
__global__ void k_gather1(const int* __restrict__ row_start, const int* __restrict__ cnt,
                          const unsigned* __restrict__ entries, const float* __restrict__ dinv,
                          const float4* __restrict__ x, float4* __restrict__ aggx) {
    int t = blockIdx.x * blockDim.x + threadIdx.x;
    int n = t >> 1, p = t & 1;
    if (n >= N_NODES) return;
    int rs = row_start[n], cn = cnt[n];
    const unsigned* ep = entries + rs;
    float4 accA = make_float4(0.f, 0.f, 0.f, 0.f);
    float4 accB = make_float4(0.f, 0.f, 0.f, 0.f);
    int i = p;
    for (; i + 6 < cn; i += 8) {
        unsigned e0 = ep[i], e1 = ep[i + 2], e2 = ep[i + 4], e3 = ep[i + 6];
        float4 v0 = x[e0 & 0xFFFFu];
        float4 v1 = x[e1 & 0xFFFFu];
        float4 v2 = x[e2 & 0xFFFFu];
        float4 v3 = x[e3 & 0xFFFFu];
        float c0 = __half2float(__ushort_as_half((unsigned short)(e0 >> 16)));
        float c1 = __half2float(__ushort_as_half((unsigned short)(e1 >> 16)));
        float c2 = __half2float(__ushort_as_half((unsigned short)(e2 >> 16)));
        float c3 = __half2float(__ushort_as_half((unsigned short)(e3 >> 16)));
        accA.x = fmaf(v0.x, c0, accA.x); accA.y = fmaf(v0.y, c0, accA.y);
        accA.z = fmaf(v0.z, c0, accA.z); accA.w = fmaf(v0.w, c0, accA.w);
        accB.x = fmaf(v1.x, c1, accB.x); accB.y = fmaf(v1.y, c1, accB.y);
        accB.z = fmaf(v1.z, c1, accB.z); accB.w = fmaf(v1.w, c1, accB.w);
        accA.x = fmaf(v2.x, c2, accA.x); accA.y = fmaf(v2.y, c2, accA.y);
        accA.z = fmaf(v2.z, c2, accA.z); accA.w = fmaf(v2.w, c2, accA.w);
        accB.x = fmaf(v3.x, c3, accB.x); accB.y = fmaf(v3.y, c3, accB.y);
        accB.z = fmaf(v3.z, c3, accB.z); accB.w = fmaf(v3.w, c3, accB.w);
    }
    for (; i < cn; i += 2) {
        unsigned e = ep[i];
        float co = __half2float(__ushort_as_half((unsigned short)(e >> 16)));
        float4 v = x[e & 0xFFFFu];
        accA.x = fmaf(v.x, co, accA.x); accA.y = fmaf(v.y, co, accA.y);
        accA.z = fmaf(v.z, co, accA.z); accA.w = fmaf(v.w, co, accA.w);
    }
    float ax = accA.x + accB.x, ay = accA.y + accB.y;
    float az = accA.z + accB.z, aw = accA.w + accB.w;
    ax += __shfl_xor(ax, 1);
    ay += __shfl_xor(ay, 1);
    az += __shfl_xor(az, 1);
    aw += __shfl_xor(aw, 1);
    if (p == 0) {
        float di = dinv[n], c = di * di;
        float4 a = x[n];
        aggx[n] = make_float4(fmaf(a.x, c, ax), fmaf(a.y, c, ay),
                              fmaf(a.z, c, az), fmaf(a.w, c, aw));
    }
}

// ---------------- BN1 stats (h1 recomputed on the fly, never stored) --------
__global__ __launch_bounds__(128) void k_stats1(const float4* __restrict__ aggx,
        const float* __restrict__ W1, const float* __restrict__ b1,
        float* __restrict__ s1, float* __restrict__ q1) {
    __shared__ float w1s[4][128];
    int j = threadIdx.x;
    for (int c = 0; c < 4; c++) w1s[c][j] = W1[c * 128 + j];
    float bj = b1[j];
    __syncthreads();
    int per = (N_NODES + gridDim.x - 1) / gridDim.x;
    int n0 = blockIdx.x * per, n1 = min(n0 + per, N_NODES);
    float ps = 0.f, pq = 0.f;
    for (int n = n0; n < n1; n++) {
        float4 a = aggx[n];
        float h = fmaf(a.x, w1s[0][j], fmaf(a.y, w1s[1][j],
                  fmaf(a.z, w1s[2][j], fmaf(a.w, w1s[3][j], bj))));
        h = fmaxf(h, 0.f);
        ps += h; pq += h * h;
    }
    atomicAdd(&s1[j], ps);
    atomicAdd(&q1[j], pq);
}

// ---------------- fold BN1 into W2 -> W2f, d2 ----------------
__global__ __launch_bounds__(128) void k_fold1(const float* __restrict__ s1,
        const float* __restrict__ q1, const float* __restrict__ g1,
        const float* __restrict__ be1, const float* __restrict__ W2,
        float* __restrict__ W2f, float* __restrict__ d2) {
    __shared__ float a[128], c[128];
    int t = threadIdx.x;
    {
        float mean = s1[t] / (float)N_NODES;
        float var  = q1[t] / (float)N_NODES - mean * mean;
        float aa   = rsqrtf(var + BN_EPS) * g1[t];
        a[t] = aa;
        c[t] = be1[t] - mean * aa;
    }
    __syncthreads();
    if (t < 64) {
        float dd = 0.f;
        for (int k = 0; k < 128; k++) {
            float wv = W2[k * 64 + t];
            W2f[k * 64 + t] = a[k] * wv;
            dd = fmaf(c[k], wv, dd);
        }
        d2[t] = dd;
    }
}

// ------- fused: recompute h1 tile from aggx, GEMM vs W2f -> h2 (fp16) ----
__global__ __launch_bounds__(256) void k_h2(const float4* __restrict__ aggx,
        const float* __restrict__ W1, const float* __restrict__ b1,
        const float* __restrict__ W2f, const float* __restrict__ d2,
        __half* __restrict__ h2) {
    __shared__ float w[128 * 64];
    __shared__ float hs[16][128];
    __shared__ float w1s[4][128];
    __shared__ float b1s[128];
    int tid = threadIdx.x;
    for (int i = tid; i < 8192; i += 256) w[i] = W2f[i];
    if (tid < 128) {
        b1s[tid] = b1[tid];
        for (int c = 0; c < 4; c++) w1s[c][tid] = W1[c * 128 + tid];
    }
    __syncthreads();
    int n0 = blockIdx.x * 16;   // grid is exactly N_NODES/16
    for (int i = tid; i < 2048; i += 256) {
        int nn = n0 + (i >> 7), j = i & 127;
        float4 a = aggx[nn];
        float h = fmaf(a.x, w1s[0][j], fmaf(a.y, w1s[1][j],
                  fmaf(a.z, w1s[2][j], fmaf(a.w, w1s[3][j], b1s[j]))));
        hs[i >> 7][j] = fmaxf(h, 0.f);
    }
    __syncthreads();
    int j = tid & 63, q = tid >> 6;
    float acc0 = 0.f, acc1 = 0.f, acc2 = 0.f, acc3 = 0.f;
    for (int k = 0; k < 128; k++) {
        float wv = w[k * 64 + j];
        acc0 = fmaf(hs[q * 4 + 0][k], wv, acc0);
        acc1 = fmaf(hs[q * 4 + 1][k], wv, acc1);
        acc2 = fmaf(hs[q * 4 + 2][k], wv, acc2);
        acc3 = fmaf(hs[q * 4 + 3][k], wv, acc3);
    }
    float dj = d2[j];
    float av[4] = {acc0, acc1, acc2, acc3};
#pragma unroll
    for (int i = 0; i < 4; i++) {
        int n = n0 + q * 4 + i;
        h2[n * 64 + j] = __float2half(av[i] + dj);
    }
}

// ------- layer-2 gather: 2 nodes/wave (32 lanes each, half2/lane),
//         4B entries, unroll-4 (4 gathers in flight), fused relu+b2+stats ----
__global__ __launch_bounds__(256) void k_gather2(const int* __restrict__ row_start,
        const int* __restrict__ cnt, const unsigned* __restrict__ entries,
        const float* __restrict__ dinv, const __half2* __restrict__ h2v,
        const float* __restrict__ b2, __half2* __restrict__ out2v,
        float* __restrict__ s2, float* __restrict__ q2) {
    int lane = threadIdx.x & 63;
    int g = lane >> 5;              // 0 = node A, 1 = node B
    int j = lane & 31;              // half2 channel-pair index (ch 2j, 2j+1)
    int wid = blockIdx.x * (blockDim.x >> 6) + (threadIdx.x >> 6);
    int nwaves = gridDim.x * (blockDim.x >> 6);
    float2 bj = make_float2(b2[2 * j], b2[2 * j + 1]);
    float2 ps = make_float2(0.f, 0.f), pq = make_float2(0.f, 0.f);

    for (int base = wid * 2; base < N_NODES; base += nwaves * 2) {
        int n = base + g;           // N even -> always valid
        int rs = row_start[n];
        int cn = cnt[n];
        float di = dinv[n];
        float sc = di * di;
        float2 self = __half22float2(h2v[n * 32 + j]);
        float2 a0 = make_float2(self.x * sc, self.y * sc);
        float2 a1 = make_float2(0.f, 0.f);
        float2 a2 = make_float2(0.f, 0.f);
        float2 a3 = make_float2(0.f, 0.f);
        int cnO = __shfl(cn, (lane + 32) & 63);
        int cm = max(cn, cnO);
        const unsigned* ep = entries + rs;
        for (int i = 0; i < cm; i += 32) {
            int um = min(32, cm - i);
            int myRem = cn - i;     // may be <=0; (j < myRem) false then
            unsigned e = (j < myRem) ? ep[i + j] : 0u;  // coef bits 0 -> fma no-op
            int k = 0;
            for (; k + 3 < um; k += 4) {
                int e0 = __shfl((int)e, k, 32);
                int e1 = __shfl((int)e, k + 1, 32);
                int e2 = __shfl((int)e, k + 2, 32);
                int e3 = __shfl((int)e, k + 3, 32);
                float2 v0 = __half22float2(h2v[(e0 & 0xFFFF) * 32 + j]);
                float2 v1 = __half22float2(h2v[(e1 & 0xFFFF) * 32 + j]);
                float2 v2 = __half22float2(h2v[(e2 & 0xFFFF) * 32 + j]);
                float2 v3 = __half22float2(h2v[(e3 & 0xFFFF) * 32 + j]);
                float c0 = __half2float(__ushort_as_half((unsigned short)((unsigned)e0 >> 16)));
                float c1 = __half2float(__ushort_as_half((unsigned short)((unsigned)e1 >> 16)));
                float c2 = __half2float(__ushort_as_half((unsigned short)((unsigned)e2 >> 16)));
                float c3 = __half2float(__ushort_as_half((unsigned short)((unsigned)e3 >> 16)));
                a0.x = fmaf(v0.x, c0, a0.x); a0.y = fmaf(v0.y, c0, a0.y);
                a1.x = fmaf(v1.x, c1, a1.x); a1.y = fmaf(v1.y, c1, a1.y);
                a2.x = fmaf(v2.x, c2, a2.x); a2.y = fmaf(v2.y, c2, a2.y);
                a3.x = fmaf(v3.x, c3, a3.x); a3.y = fmaf(v3.y, c3, a3.y);
            }
            for (; k < um; k++) {
                int e0 = __shfl((int)e, k, 32);
                float c0 = __half2float(__ushort_as_half((unsigned short)((unsigned)e0 >> 16)));
                float2 v0 = __half22float2(h2v[(e0 & 0xFFFF) * 32 + j]);
                a0.x = fmaf(v0.x, c0, a0.x); a0.y = fmaf(v0.y, c0, a0.y);
            }
        }
        float vx = fmaxf(a0.x + a1.x + a2.x + a3.x + bj.x, 0.f);
        float vy = fmaxf(a0.y + a1.y + a2.y + a3.y + bj.y, 0.f);
        out2v[n * 32 + j] = __floats2half2_rn(vx, vy);
        ps.x += vx; ps.y += vy;
        pq.x += vx * vx; pq.y += vy * vy;
    }
    __shared__ float ssum[64], sq[64];
    if (threadIdx.x < 64) { ssum[threadIdx.x] = 0.f; sq[threadIdx.x] = 0.f; }
    __syncthreads();
    atomicAdd(&ssum[2 * j], ps.x);
    atomicAdd(&ssum[2 * j + 1], ps.y);
    atomicAdd(&sq[2 * j], pq.x);
    atomicAdd(&sq[2 * j + 1], pq.y);
    __syncthreads();
    if (threadIdx.x < 64) {
        atomicAdd(&s2[threadIdx.x], ssum[threadIdx.x]);
        atomicAdd(&q2[threadIdx.x], sq[threadIdx.x]);
    }
}

// ---- global_add_pool (batch sorted: run-accumulate), BN2 affine fused ----
__global__ __launch_bounds__(64) void k_pool(const __half* __restrict__ out2,
        const int* __restrict__ batch, const float* __restrict__ s2,
        const float* __restrict__ q2, const float* __restrict__ g2,
        const float* __restrict__ be2, float* __restrict__ hg) {
    int j = threadIdx.x;
    float mean = s2[j] / (float)N_NODES;
    float var  = q2[j] / (float)N_NODES - mean * mean;
    float a = rsqrtf(var + BN_EPS) * g2[j];
    float c = be2[j] - mean * a;
    int per = (N_NODES + gridDim.x - 1) / gridDim.x;
    int n0 = blockIdx.x * per, n1 = min(n0 + per, N_NODES);
    float acc = 0.f;
    int cur = -1;
    for (int n = n0; n < n1; n++) {
        int g = batch[n];
        float v = fmaf(__half2float(out2[n * 64 + j]), a, c);
        if (g != cur) {
            if (cur >= 0) atomicAdd(&hg[cur * 64 + j], acc);
            cur = g; acc = v;
        } else {
            acc += v;
        }
    }
    if (cur >= 0) atomicAdd(&hg[cur * 64 + j], acc);
}

// ---------------- fc1 + relu + BN3 stats ----------------
__global__ __launch_bounds__(256) void k_fc1(const float* __restrict__ hg,
        const float* __restrict__ fW1, const float* __restrict__ fb1,
        float* __restrict__ t1, float* __restrict__ s3, float* __restrict__ q3) {
    __shared__ float w[64 * 64];
    int tid = threadIdx.x;
    for (int i = tid; i < 4096; i += 256) w[i] = fW1[i];
    __syncthreads();
    int j = tid & 63, q = tid >> 6;
    float bj = fb1[j];
    float ps = 0.f, pq = 0.f;
    for (int r = blockIdx.x * 4 + q; r < NGRAPH; r += gridDim.x * 4) {
        float acc = bj;
        for (int k = 0; k < 64; k++) acc = fmaf(hg[r * 64 + k], w[k * 64 + j], acc);
        acc = fmaxf(acc, 0.f);
        t1[r * 64 + j] = acc;
        ps += acc; pq += acc * acc;
    }
    atomicAdd(&s3[j], ps);
    atomicAdd(&q3[j], pq);
}

// ------- bn3 (affine from stats, fused) -> fc2+relu -> fc3 -> log_softmax ---
__global__ __launch_bounds__(256) void k_final(const float* __restrict__ t1,
        const float* __restrict__ s3, const float* __restrict__ q3,
        const float* __restrict__ g3, const float* __restrict__ be3,
        const float* __restrict__ fW2, const float* __restrict__ fb2,
        const float* __restrict__ fW3, const float* __restrict__ fb3,
        float* __restrict__ out) {
    __shared__ float w2[64 * 64];
    __shared__ float w3s[192];
    __shared__ float a3[64], c3[64], b3s[3];
    int tid = threadIdx.x;
    for (int i = tid; i < 4096; i += 256) w2[i] = fW2[i];
    if (tid < 192) w3s[tid] = fW3[tid];
    if (tid < 64) {
        float mean = s3[tid] / (float)NGRAPH;
        float var  = q3[tid] / (float)NGRAPH - mean * mean;
        float a = rsqrtf(var + BN_EPS) * g3[tid];
        a3[tid] = a;
        c3[tid] = be3[tid] - mean * a;
    }
    if (tid < 3)  b3s[tid] = fb3[tid];
    __syncthreads();
    int lane = tid & 63, wv = tid >> 6;
    float fbj = fb2[lane];
    for (int r = blockIdx.x * 4 + wv; r < NGRAPH; r += gridDim.x * 4) {
        float acc = fbj;
        for (int k = 0; k < 64; k++) {
            float xk = fmaf(t1[r * 64 + k], a3[k], c3[k]);
            acc = fmaf(xk, w2[k * 64 + lane], acc);
        }
        acc = fmaxf(acc, 0.f);
        float o0 = acc * w3s[lane * 3 + 0];
        float o1 = acc * w3s[lane * 3 + 1];
        float o2 = acc * w3s[lane * 3 + 2];
        for (int off = 32; off; off >>= 1) {
            o0 += __shfl_down(o0, off);
            o1 += __shfl_down(o1, off);
            o2 += __shfl_down(o2, off);
        }
        if (lane == 0) {
            o0 += b3s[0]; o1 += b3s[1]; o2 += b3s[2];
            float m = fmaxf(o0, fmaxf(o1, o2));
            float lse = m + logf(expf(o0 - m) + expf(o1 - m) + expf(o2 - m));
            out[r * 3 + 0] = o0 - lse;
            out[r * 3 + 1] = o1 - lse;
            out[r * 3 + 2] = o2 - lse;
        }
    }
}

extern "C" void kernel_launch(void* const* d_in, const int* in_sizes, int n_in,
                              void* d_out, int out_size, void* d_ws, size_t ws_size,
                              hipStream_t stream) {
    const float* x   = (const float*)d_in[0];
    const int*   ei  = (const int*)d_in[1];
    const int*   bat = (const int*)d_in[2];
    const float* W1  = (const float*)d_in[3];
    const float* b1  = (const float*)d_in[4];
    const float* g1  = (const float*)d_in[5];
    const float* be1 = (const float*)d_in[6];
    const float* W2  = (const float*)d_in[7];
    const float* b2  = (const float*)d_in[8];
    const float* g2  = (const float*)d_in[9];
    const float* be2 = (const float*)d_in[10];
    const float* fW1 = (const float*)d_in[11];
    const float* fb1 = (const float*)d_in[12];
    const float* g3  = (const float*)d_in[13];
    const float* be3 = (const float*)d_in[14];
    const float* fW2 = (const float*)d_in[15];
    const float* fb2 = (const float*)d_in[16];
    const float* fW3 = (const float*)d_in[17];
    const float* fb3 = (const float*)d_in[18];

    // ---- workspace layout ----
    // zeroed region: cnt | cursor | hg | s1 q1 s2 q2 s3 q3
    int*   cnt    = (int*)d_ws;                       // N
    int*   cursor = cnt + N_NODES;                    // N
    float* hg     = (float*)(cursor + N_NODES);       // 512*64
    float* s1     = hg + NGRAPH * 64;                 // 128
    float* q1     = s1 + 128;                         // 128
    float* s2     = q1 + 128;                         // 64
    float* q2     = s2 + 64;                          // 64
    float* s3     = q2 + 64;                          // 64
    float* q3     = s3 + 64;                          // 64
    size_t zero_bytes = ((size_t)N_NODES * 2 + NGRAPH * 64 + 512) * 4;
    // non-zeroed scratch
    float* dinv   = q3 + 64;                          // N
    int*   row_start = (int*)(dinv + N_NODES);        // N
    int*   slocal = row_start + N_NODES;              // N   (scan locals)
    int*   sbsum  = slocal + N_NODES;                 // SCAN_BLOCKS (pad 256)
    unsigned* entries = (unsigned*)(sbsum + 256);     // E (4B each)
    float* aggx   = (float*)(entries + N_EDGES);      // N*4 (16B aligned)
    __half* h2    = (__half*)(aggx + (size_t)N_NODES * 4);   // [N][64] halfs
    __half* out2  = h2 + (size_t)N_NODES * 64;        // [N][64] halfs
    float* W2f    = (float*)(out2 + (size_t)N_NODES * 64);   // 128*64
    float* d2     = W2f + 128 * 64;                   // 64
    float* t1     = d2 + 64;                          // 512*64

    hipMemsetAsync(d_ws, 0, zero_bytes, stream);

    const int* src = ei;
    const int* dst = ei + N_EDGES;

    k_deg    <<<(N_EDGES + 255) / 256, 256, 0, stream>>>(dst, cnt);
    k_scanA  <<<SCAN_BLOCKS, 256, 0, stream>>>(cnt, dinv, slocal, sbsum);
    k_scanBC <<<SCAN_BLOCKS, 256, 0, stream>>>(sbsum, slocal, row_start);
    k_fill   <<<(N_EDGES + 255) / 256, 256, 0, stream>>>(src, dst, row_start, cursor, dinv, entries);
    k_gather1<<<(2 * N_NODES + 255) / 256, 256, 0, stream>>>(row_start, cnt, entries, dinv, (const float4*)x, (float4*)aggx);
    k_stats1 <<<512, 128, 0, stream>>>((const float4*)aggx, W1, b1, s1, q1);
    k_fold1  <<<1, 128, 0, stream>>>(s1, q1, g1, be1, W2, W2f, d2);
    k_h2     <<<N_NODES / 16, 256, 0, stream>>>((const float4*)aggx, W1, b1, W2f, d2, h2);
    k_gather2<<<2048, 256, 0, stream>>>(row_start, cnt, entries, dinv, (const __half2*)h2, b2, (__half2*)out2, s2, q2);
    k_pool   <<<1024, 64, 0, stream>>>(out2, bat, s2, q2, g2, be2, hg);
    k_fc1    <<<16, 256, 0, stream>>>(hg, fW1, fb1, t1, s3, q3);
    k_final  <<<16, 256, 0, stream>>>(t1, s3, q3, g3, be3, fW2, fb2, fW3, fb3, (float*)d_out);
}